// Round 6
// baseline (406.756 us; speedup 1.0000x reference)
//
#include <hip/hip_runtime.h>
#include <math.h>

#define D_MODEL 512
#define BATCH 8
#define SEQ 512
#define HEAD 64
#define DK 4
#define DV 8
#define HIDD 10

// proj tiled-GEMM params: 64x128 block tile, ONE wave/block, 16x8 per-thread
// register tile. Rationale (LDS-inst model, fitted r0/r1/r4/r5): each
// ds_read_b128 costs ~12 cyc of the CU-shared LDS pipe regardless of lane
// duplication -> need RC >= 6(R+C); 16x8 is the smallest tile that fits.
#define PMR 64
#define PNC 128
#define PKC 32

__device__ __forceinline__ float4 fma4(float s, float4 w, float4 a) {
    a.x = fmaf(s, w.x, a.x); a.y = fmaf(s, w.y, a.y);
    a.z = fmaf(s, w.z, a.z); a.w = fmaf(s, w.w, a.w);
    return a;
}

// ---------------------------------------------------------------------------
// proj: self Q/K/V from x + cross K/V from x_enc. 14 col-jobs (NC=128) x
// 64 row-blocks = 896 one-wave blocks (3.5 waves/CU: LDS demand 3.5x6x12
// ~= 252 cyc per 256-cyc FMA window -> balanced, vs 2.25x oversub at r5's
// 8x4 tile). XCD-swizzled so the 14 jobs sharing an x row-block run on one
// XCD (W 3.5 MB stays L2-resident). Outputs head-major.
// ---------------------------------------------------------------------------
__global__ __launch_bounds__(64, 2) void proj_kernel(
    const float* __restrict__ x, const float* __restrict__ xe,
    const float* __restrict__ Wq, const float* __restrict__ Wk,
    const float* __restrict__ Wv,
    float* __restrict__ Q2, float* __restrict__ K2, float* __restrict__ V2,
    float* __restrict__ Kc, float* __restrict__ Vc)
{
    __shared__ float xt[PKC][PMR];   // [k][r]  8 KB
    __shared__ float wt[PKC][PNC];   // [k][c] 16 KB

    const int t = threadIdx.x;
    // bijective XCD swizzle (m204, 896 = 8*112): each XCD gets contiguous
    // row-block groups; the 14 col-jobs of a row-block share its x rows.
    const int swz = (blockIdx.x & 7) * 112 + (blockIdx.x >> 3);
    const int bj = swz % 14;
    const int br = swz / 14;
    const int r0 = br * PMR;

    const float* X; const float* W; int ldw; int c0; float* dst; int vt;
    if (bj < 2)       { X = x;  W = Wq; ldw = 256; c0 = bj * 128;         dst = Q2; vt = 0; }
    else if (bj < 4)  { X = x;  W = Wk; ldw = 256; c0 = (bj - 2) * 128;   dst = K2; vt = 0; }
    else if (bj < 8)  { X = x;  W = Wv; ldw = 512; c0 = (bj - 4) * 128;   dst = V2; vt = 1; }
    else if (bj < 10) { X = xe; W = Wk; ldw = 256; c0 = (bj - 8) * 128;   dst = Kc; vt = 0; }
    else              { X = xe; W = Wv; ldw = 512; c0 = (bj - 10) * 128;  dst = Vc; vt = 1; }

    const int rg = t >> 4;          // 0..3 -> rows rg*16 .. rg*16+15
    const int cq = t & 15;          // cols cq*4..+3 and 64+cq*4..+3

    float4 acc[16][2];
#pragma unroll
    for (int r = 0; r < 16; ++r) {
        acc[r][0] = make_float4(0.f, 0.f, 0.f, 0.f);
        acc[r][1] = make_float4(0.f, 0.f, 0.f, 0.f);
    }

    for (int kc = 0; kc < D_MODEL; kc += PKC) {
        // ---- stage x tile transposed [k][r]: lane = row, 8 float4 along k
        {
            const float* xr = X + (long)(r0 + t) * D_MODEL + kc;
#pragma unroll
            for (int i = 0; i < 8; ++i) {
                const float4 v = *(const float4*)(xr + i * 4);
                xt[i * 4 + 0][t] = v.x;
                xt[i * 4 + 1][t] = v.y;
                xt[i * 4 + 2][t] = v.z;
                xt[i * 4 + 3][t] = v.w;
            }
        }
        // ---- stage W tile [k][c]: 16 float4 per lane, conflict-free
        {
            const int cw = (t & 31) * 4;        // col quad 0..124
            const int k0 = t >> 5;              // 0..1
#pragma unroll
            for (int i = 0; i < 16; ++i) {
                const int kr = k0 + i * 2;
                *(float4*)(&wt[kr][cw]) =
                    *(const float4*)(W + (long)(kc + kr) * ldw + c0 + cw);
            }
        }
        __syncthreads();

#pragma unroll 2
        for (int k = 0; k < PKC; ++k) {
            const float4 x0 = *(const float4*)(&xt[k][rg * 16 + 0]);
            const float4 x1 = *(const float4*)(&xt[k][rg * 16 + 4]);
            const float4 x2 = *(const float4*)(&xt[k][rg * 16 + 8]);
            const float4 x3 = *(const float4*)(&xt[k][rg * 16 + 12]);
            const float4 w0 = *(const float4*)(&wt[k][cq * 4]);
            const float4 w1 = *(const float4*)(&wt[k][64 + cq * 4]);
            const float xv[16] = {x0.x, x0.y, x0.z, x0.w,
                                  x1.x, x1.y, x1.z, x1.w,
                                  x2.x, x2.y, x2.z, x2.w,
                                  x3.x, x3.y, x3.z, x3.w};
#pragma unroll
            for (int r = 0; r < 16; ++r) {
                acc[r][0] = fma4(xv[r], w0, acc[r][0]);
                acc[r][1] = fma4(xv[r], w1, acc[r][1]);
            }
        }
        __syncthreads();
    }

    // ---- epilogue: head-major scatter ----
    const int b = r0 >> 9;              // 64-row block stays within one b
    if (vt == 0) {
#pragma unroll
        for (int ci = 0; ci < 2; ++ci) {
            const int h = (c0 >> 2) + ci * 16 + cq;   // f4 = full (s,h) row
#pragma unroll
            for (int r = 0; r < 16; ++r) {
                const int s = (r0 & 511) + rg * 16 + r;
                *(float4*)(dst + (((long)b * HEAD + h) * SEQ + s) * 4) = acc[r][ci];
            }
        }
    } else {
#pragma unroll
        for (int ci = 0; ci < 2; ++ci) {
            const int c = c0 + ci * 64 + cq * 4;
            const int h = c >> 3;
            const int off = c & 7;      // 0 or 4
#pragma unroll
            for (int r = 0; r < 16; ++r) {
                const int s = (r0 & 511) + rg * 16 + r;
                *(float4*)(dst + (((long)b * HEAD + h) * SEQ + s) * 8 + off) = acc[r][ci];
            }
        }
    }
}

// ---------------------------------------------------------------------------
// proj2 (r5-proven): Q only — attn1's output A is consumed solely as the
// stage-2 query. Split-K x2 (kh=0 -> Qa, kh=1 -> Qb; attn sums on load).
// ---------------------------------------------------------------------------
__global__ __launch_bounds__(256, 8) void proj2_kernel(
    const float* __restrict__ A, const float* __restrict__ Wq,
    float* __restrict__ Qa, float* __restrict__ Qb)
{
    __shared__ float xt[32 * 32];   // 4 KB
    __shared__ float wt[32 * 64];   // 8 KB

    const int t  = threadIdx.x;
    const int kh = blockIdx.x & 1;
    const int bj = (blockIdx.x >> 1) & 3;
    const int br = blockIdx.x >> 3;
    const int r0 = br * 32;
    const int c0 = bj * 64;
    const int kb = kh * 256;
    float* dst = kh ? Qb : Qa;

    const int cq = t & 15;          // cols cq*4..+3 (64 cols)
    const int rr = t >> 4;          // rows rr*2..+1
    const int rs = t & 31, kq = t >> 5;

    float4 acc[2];
    acc[0] = make_float4(0.f, 0.f, 0.f, 0.f);
    acc[1] = acc[0];

    for (int kc = 0; kc < 256; kc += 32) {
        const float4 xa = *(const float4*)(A + (long)(r0 + rs) * D_MODEL + kb + kc + kq * 4);
        xt[(kq * 4 + 0) * 32 + rs] = xa.x;
        xt[(kq * 4 + 1) * 32 + rs] = xa.y;
        xt[(kq * 4 + 2) * 32 + rs] = xa.z;
        xt[(kq * 4 + 3) * 32 + rs] = xa.w;
#pragma unroll
        for (int i = 0; i < 2; ++i) {
            const int row = i * 16 + (t >> 4);
            *(float4*)(wt + row * 64 + (t & 15) * 4) =
                *(const float4*)(Wq + (long)(kb + kc + row) * 256 + c0 + (t & 15) * 4);
        }
        __syncthreads();
#pragma unroll 4
        for (int k = 0; k < 32; ++k) {
            const float4 w4 = *(const float4*)(wt + k * 64 + cq * 4);
            const float2 x2 = *(const float2*)(xt + k * 32 + rr * 2);
            acc[0] = fma4(x2.x, w4, acc[0]);
            acc[1] = fma4(x2.y, w4, acc[1]);
        }
        __syncthreads();
    }

    const int b  = r0 >> 9;
    const int sb = (r0 & 511) + rr * 2;
    const int h  = (c0 >> 2) + cq;
#pragma unroll
    for (int r = 0; r < 2; ++r)
        *(float4*)(dst + (((long)b * HEAD + h) * SEQ + sb + r) * 4) = acc[r];
}

// ---------------------------------------------------------------------------
// Attention (r5-proven): one block per (b, h, q-half); 256 threads, 1 query
// per thread. Online softmax in the LOG2 domain. Causal quirk preserved:
// masked scores are exactly 0 and participate; lump = 2^(-M)*(count, sufV).
// ---------------------------------------------------------------------------
__global__ __launch_bounds__(256) void attn_kernel(
    const float* __restrict__ Qa, const float* __restrict__ Qb,
    const float* __restrict__ K2, const float* __restrict__ V2,
    float* __restrict__ O, int causal)
{
    extern __shared__ float smem[];
    float* Kl = smem;                 // SEQ*DK = 2048 floats
    float* Vl = smem + SEQ * DK;      // SEQ*DV = 4096 floats
    float* cs = Vl + SEQ * DV;        // 33*DV  =  264 floats (causal only)

    const int t = threadIdx.x;
    const int bh = blockIdx.x >> 1;   // b*64 + h
    const int qhalf = blockIdx.x & 1;
    const int b = bh >> 6;
    const int h = bh & 63;

    const float4* Ks = (const float4*)(K2 + (long)bh * SEQ * DK);
    ((float4*)Kl)[t]       = Ks[t];
    ((float4*)Kl)[t + 256] = Ks[t + 256];
    const float4* Vs = (const float4*)(V2 + (long)bh * SEQ * DV);
#pragma unroll
    for (int i = 0; i < 4; ++i)
        ((float4*)Vl)[t + i * 256] = Vs[t + i * 256];
    __syncthreads();

    if (causal) {
        const int ch = t >> 3, d = t & 7;
        float s16 = 0.f;
#pragma unroll
        for (int i = 0; i < 16; ++i) s16 += Vl[(ch * 16 + i) * 8 + d];
        cs[ch * 8 + d] = s16;
        __syncthreads();
        if (t < 8) {
            cs[256 + t] = 0.f;
            float run = 0.f;
            for (int c2 = 31; c2 >= 0; --c2) {
                run += cs[c2 * 8 + t];
                cs[c2 * 8 + t] = run;
            }
        }
        __syncthreads();
    }

    const int q = qhalf * 256 + t;
    float4 qv = *(const float4*)(Qa + ((long)bh * SEQ + q) * 4);
    if (Qb) {
        const float4 qw = *(const float4*)(Qb + ((long)bh * SEQ + q) * 4);
        qv.x += qw.x; qv.y += qw.y; qv.z += qw.z; qv.w += qw.w;
    }
    const float cf = 0.5f * 1.44269504088896340736f;  // 1/sqrt(DK) * log2(e)
    const float q0 = qv.x * cf, q1 = qv.y * cf;
    const float q2 = qv.z * cf, q3 = qv.w * cf;

    const int bound = causal ? q : (SEQ - 1);

    float m = -INFINITY, l = 0.f;
    float a0=0.f,a1=0.f,a2=0.f,a3=0.f,a4=0.f,a5=0.f,a6=0.f,a7=0.f;

    int s0 = 0;
    for (; s0 + 8 <= bound + 1; s0 += 8) {
        float sc[8];
#pragma unroll
        for (int i = 0; i < 8; ++i) {
            const float4 k4 = *(const float4*)(Kl + (s0 + i) * 4);
            sc[i] = fmaf(q0, k4.x, fmaf(q1, k4.y, fmaf(q2, k4.z, q3 * k4.w)));
        }
        float gm = fmaxf(fmaxf(fmaxf(sc[0], sc[1]), fmaxf(sc[2], sc[3])),
                         fmaxf(fmaxf(sc[4], sc[5]), fmaxf(sc[6], sc[7])));
        if (gm > m) {
            float scale = __builtin_amdgcn_exp2f(m - gm);
            l *= scale;
            a0*=scale; a1*=scale; a2*=scale; a3*=scale;
            a4*=scale; a5*=scale; a6*=scale; a7*=scale;
            m = gm;
        }
#pragma unroll
        for (int i = 0; i < 8; ++i) {
            float p = __builtin_amdgcn_exp2f(sc[i] - m);
            l += p;
            const float4 v0 = *(const float4*)(Vl + (s0 + i) * 8);
            const float4 v1 = *(const float4*)(Vl + (s0 + i) * 8 + 4);
            a0 = fmaf(p, v0.x, a0); a1 = fmaf(p, v0.y, a1);
            a2 = fmaf(p, v0.z, a2); a3 = fmaf(p, v0.w, a3);
            a4 = fmaf(p, v1.x, a4); a5 = fmaf(p, v1.y, a5);
            a6 = fmaf(p, v1.z, a6); a7 = fmaf(p, v1.w, a7);
        }
    }
    for (int s = s0; s <= bound; ++s) {
        const float4 k4 = *(const float4*)(Kl + s * 4);
        float sc = fmaf(q0, k4.x, fmaf(q1, k4.y, fmaf(q2, k4.z, q3 * k4.w)));
        if (sc > m) {
            float scale = __builtin_amdgcn_exp2f(m - sc);
            l *= scale;
            a0*=scale; a1*=scale; a2*=scale; a3*=scale;
            a4*=scale; a5*=scale; a6*=scale; a7*=scale;
            m = sc;
        }
        float p = __builtin_amdgcn_exp2f(sc - m);
        l += p;
        const float4 v0 = *(const float4*)(Vl + s * 8);
        const float4 v1 = *(const float4*)(Vl + s * 8 + 4);
        a0 = fmaf(p, v0.x, a0); a1 = fmaf(p, v0.y, a1);
        a2 = fmaf(p, v0.z, a2); a3 = fmaf(p, v0.w, a3);
        a4 = fmaf(p, v1.x, a4); a5 = fmaf(p, v1.y, a5);
        a6 = fmaf(p, v1.z, a6); a7 = fmaf(p, v1.w, a7);
    }

    if (causal && q < SEQ - 1) {
        float M = fmaxf(m, 0.f);               // masked keys contribute t=0
        float scale = __builtin_amdgcn_exp2f(m - M);
        float pm = __builtin_amdgcn_exp2f(-M);
        l = l * scale + pm * (float)(SEQ - 1 - q);
        int nq = q + 1;
        int cq2 = nq >> 4;
        float sv[8];
#pragma unroll
        for (int d = 0; d < 8; ++d) sv[d] = cs[(cq2 + 1) * 8 + d];
        for (int s = nq; s < (cq2 + 1) * 16; ++s) {
            const float4 v0 = *(const float4*)(Vl + s * 8);
            const float4 v1 = *(const float4*)(Vl + s * 8 + 4);
            sv[0]+=v0.x; sv[1]+=v0.y; sv[2]+=v0.z; sv[3]+=v0.w;
            sv[4]+=v1.x; sv[5]+=v1.y; sv[6]+=v1.z; sv[7]+=v1.w;
        }
        a0 = a0*scale + pm*sv[0]; a1 = a1*scale + pm*sv[1];
        a2 = a2*scale + pm*sv[2]; a3 = a3*scale + pm*sv[3];
        a4 = a4*scale + pm*sv[4]; a5 = a5*scale + pm*sv[5];
        a6 = a6*scale + pm*sv[6]; a7 = a7*scale + pm*sv[7];
    }

    float inv = 1.0f / l;
    const long obase = (long)b * SEQ * 512 + (long)q * 512 + h * DV;
    *(float4*)(O + obase)     = make_float4(a0*inv, a1*inv, a2*inv, a3*inv);
    *(float4*)(O + obase + 4) = make_float4(a4*inv, a5*inv, a6*inv, a7*inv);
}

// ---------------------------------------------------------------------------
// Fused residual + LayerNorm + MLP (512 -> 10 -> 512), r5-proven.
// ---------------------------------------------------------------------------
__global__ __launch_bounds__(256) void ln_mlp_kernel(
    const float* __restrict__ x, const float* __restrict__ fx,
    const float* __restrict__ g, const float* __restrict__ beta,
    const float* __restrict__ w1, const float* __restrict__ b1,
    const float* __restrict__ w2, const float* __restrict__ b2,
    float* __restrict__ out)
{
    const int t = threadIdx.x;
    const int lane = t & 63;
    const int row = blockIdx.x * 4 + (t >> 6);
    const long base = (long)row * D_MODEL;
    const int e0 = lane * 8;

    const float4 xa = *(const float4*)(x + base + e0);
    const float4 xb = *(const float4*)(x + base + e0 + 4);
    const float4 fa = *(const float4*)(fx + base + e0);
    const float4 fb = *(const float4*)(fx + base + e0 + 4);
    float z[8] = {xa.x+fa.x, xa.y+fa.y, xa.z+fa.z, xa.w+fa.w,
                  xb.x+fb.x, xb.y+fb.y, xb.z+fb.z, xb.w+fb.w};

    float sum = 0.f;
#pragma unroll
    for (int j = 0; j < 8; ++j) sum += z[j];
#pragma unroll
    for (int o = 32; o > 0; o >>= 1) sum += __shfl_xor(sum, o);
    float mu = sum * (1.0f / 512.0f);

    float d[8], ss = 0.f;
#pragma unroll
    for (int j = 0; j < 8; ++j) { d[j] = z[j] - mu; ss += d[j] * d[j]; }
#pragma unroll
    for (int o = 32; o > 0; o >>= 1) ss += __shfl_xor(ss, o);
    float rs = rsqrtf(ss * (1.0f / 512.0f) + 1e-5f);

    const float4 ga = *(const float4*)(g + e0);
    const float4 gb = *(const float4*)(g + e0 + 4);
    const float4 ba = *(const float4*)(beta + e0);
    const float4 bb = *(const float4*)(beta + e0 + 4);
    const float gg[8] = {ga.x,ga.y,ga.z,ga.w,gb.x,gb.y,gb.z,gb.w};
    const float bt[8] = {ba.x,ba.y,ba.z,ba.w,bb.x,bb.y,bb.z,bb.w};
    float y[8];
#pragma unroll
    for (int j = 0; j < 8; ++j) y[j] = d[j] * rs * gg[j] + bt[j];

    float part[HIDD];
#pragma unroll
    for (int i = 0; i < HIDD; ++i) {
        const float4 wa = *(const float4*)(w1 + i * 512 + e0);
        const float4 wb = *(const float4*)(w1 + i * 512 + e0 + 4);
        part[i] = y[0]*wa.x + y[1]*wa.y + y[2]*wa.z + y[3]*wa.w
                + y[4]*wb.x + y[5]*wb.y + y[6]*wb.z + y[7]*wb.w;
    }
#pragma unroll
    for (int i = 0; i < HIDD; ++i)
#pragma unroll
        for (int o = 32; o > 0; o >>= 1) part[i] += __shfl_xor(part[i], o);

    float hv[HIDD];
#pragma unroll
    for (int i = 0; i < HIDD; ++i) hv[i] = fmaxf(part[i] + b1[i], 0.f);

    float o8[8];
#pragma unroll
    for (int j = 0; j < 8; ++j) o8[j] = b2[e0 + j];
#pragma unroll
    for (int i = 0; i < HIDD; ++i)
#pragma unroll
        for (int j = 0; j < 8; ++j)
            o8[j] = fmaf(hv[i], w2[(long)(e0 + j) * 10 + i], o8[j]);

    *(float4*)(out + base + e0)     = make_float4(o8[0], o8[1], o8[2], o8[3]);
    *(float4*)(out + base + e0 + 4) = make_float4(o8[4], o8[5], o8[6], o8[7]);
}

extern "C" void kernel_launch(void* const* d_in, const int* in_sizes, int n_in,
                              void* d_out, int out_size, void* d_ws, size_t ws_size,
                              hipStream_t stream) {
    (void)in_sizes; (void)n_in; (void)out_size; (void)ws_size;
    const float* x    = (const float*)d_in[0];
    const float* xenc = (const float*)d_in[1];
    const float* Wq   = (const float*)d_in[2];
    const float* Wk   = (const float*)d_in[3];
    const float* Wv   = (const float*)d_in[4];
    const float* ln_g = (const float*)d_in[5];
    const float* ln_b = (const float*)d_in[6];
    const float* w1   = (const float*)d_in[7];
    const float* b1   = (const float*)d_in[8];
    const float* w2   = (const float*)d_in[9];
    const float* b2   = (const float*)d_in[10];
    float* out = (float*)d_out;

    // Workspace: 11.5M floats = 46 MiB, all regions disjoint (r5-proven).
    float* ws = (float*)d_ws;
    float* Q1 = ws;                    // [ 0M, 1M)  self Q   head-major
    float* K1 = ws +  1048576;         // [ 1M, 2M)  self K
    float* V1 = ws +  2097152;         // [ 2M, 4M)  self V
    float* Kc = ws +  4194304;         // [ 4M, 5M)  cross K (from x_enc)
    float* Vc = ws +  5242880;         // [ 5M, 7M)  cross V
    float* A  = ws +  7340032;         // [ 7M, 9M)  attn out, row-major
    float* Qa = ws +  9437184;         // [ 9M,10M)  stage-2 Q, k-half 0
    float* Qb = ws + 10485760;         // [10M,11M)  stage-2 Q, k-half 1

    const size_t lds_cross  = (size_t)(SEQ * DK + SEQ * DV) * 4;          // 24576
    const size_t lds_causal = lds_cross + (size_t)(33 * DV) * 4;          // 25632

    proj_kernel<<<dim3(896), 64, 0, stream>>>(x, xenc, Wq, Wk, Wv,
                                              Q1, K1, V1, Kc, Vc);
    attn_kernel<<<dim3(BATCH * HEAD * 2), 256, lds_causal, stream>>>(
        Q1, nullptr, K1, V1, A, 1);
    proj2_kernel<<<dim3(1024), 256, 0, stream>>>(A, Wq, Qa, Qb);
    attn_kernel<<<dim3(BATCH * HEAD * 2), 256, lds_cross, stream>>>(
        Qa, Qb, Kc, Vc, A, 0);
    ln_mlp_kernel<<<dim3(1024), 256, 0, stream>>>(x, A, ln_g, ln_b,
                                                  w1, b1, w2, b2, out);
}

// Round 7
// 353.080 us; speedup vs baseline: 1.1520x; 1.1520x over previous
//
#include <hip/hip_runtime.h>
#include <math.h>

#define D_MODEL 512
#define BATCH 8
#define SEQ 512
#define HEAD 64
#define DK 4
#define DV 8
#define HIDD 10

// proj tiled-GEMM params (r5-proven best: 121 us measured; FROZEN)
#define MR 32    // rows per block
#define KC 32    // k-chunk
#define NC 256   // cols per block (36 KB LDS)

__device__ __forceinline__ float4 fma4(float s, float4 w, float4 a) {
    a.x = fmaf(s, w.x, a.x); a.y = fmaf(s, w.y, a.y);
    a.z = fmaf(s, w.z, a.z); a.w = fmaf(s, w.w, a.w);
    return a;
}

// ---------------------------------------------------------------------------
// proj (r5-proven, FROZEN): self Q/K/V from x + cross K/V from x_enc in one
// launch. 7 col-jobs x 128 row-blocks = 896 blocks. Outputs head-major.
// ---------------------------------------------------------------------------
__global__ __launch_bounds__(256) void proj_kernel(
    const float* __restrict__ x, const float* __restrict__ xe,
    const float* __restrict__ Wq, const float* __restrict__ Wk,
    const float* __restrict__ Wv,
    float* __restrict__ Q2, float* __restrict__ K2, float* __restrict__ V2,
    float* __restrict__ Kc, float* __restrict__ Vc)
{
    __shared__ float xt[KC * MR];   // [k][r]  4 KB
    __shared__ float wt[KC * NC];   // [k][c] 32 KB

    const int t  = threadIdx.x;
    const int bj = blockIdx.x >> 7;      // 0..6 col-job
    const int br = blockIdx.x & 127;     // row block
    const int r0 = br * MR;

    const float* X; const float* W; int ldw; int c0; float* dst; int vt;
    switch (bj) {
      case 0:  X = x;  W = Wq; ldw = 256; c0 = 0;   dst = Q2; vt = 0; break;
      case 1:  X = x;  W = Wk; ldw = 256; c0 = 0;   dst = K2; vt = 0; break;
      case 2:  X = x;  W = Wv; ldw = 512; c0 = 0;   dst = V2; vt = 1; break;
      case 3:  X = x;  W = Wv; ldw = 512; c0 = 256; dst = V2; vt = 1; break;
      case 4:  X = xe; W = Wk; ldw = 256; c0 = 0;   dst = Kc; vt = 0; break;
      case 5:  X = xe; W = Wv; ldw = 512; c0 = 0;   dst = Vc; vt = 1; break;
      default: X = xe; W = Wv; ldw = 512; c0 = 256; dst = Vc; vt = 1; break;
    }

    const int rg = t >> 6;          // wave id -> rows rg*8..rg*8+7
    const int cq = t & 63;          // cols cq*4..cq*4+3
    const int rs = t & 31;          // x-staging: row
    const int kq = t >> 5;          // x-staging: k-quad 0..7

    float4 acc[8];
#pragma unroll
    for (int r = 0; r < 8; ++r) acc[r] = make_float4(0.f, 0.f, 0.f, 0.f);

    for (int kc = 0; kc < D_MODEL; kc += KC) {
        const float4 xa = *(const float4*)(X + (long)(r0 + rs) * D_MODEL + kc + kq * 4);
        xt[(kq * 4 + 0) * MR + rs] = xa.x;
        xt[(kq * 4 + 1) * MR + rs] = xa.y;
        xt[(kq * 4 + 2) * MR + rs] = xa.z;
        xt[(kq * 4 + 3) * MR + rs] = xa.w;

#pragma unroll
        for (int i = 0; i < 8; ++i) {
            const int row = i * 4 + rg;
            *(float4*)(wt + row * NC + cq * 4) =
                *(const float4*)(W + (long)(kc + row) * ldw + c0 + cq * 4);
        }
        __syncthreads();

#pragma unroll 4
        for (int k = 0; k < KC; ++k) {
            const float4 w4 = *(const float4*)(wt + k * NC + cq * 4);
            const float4 x0 = *(const float4*)(xt + k * MR + rg * 8);
            const float4 x1 = *(const float4*)(xt + k * MR + rg * 8 + 4);
            acc[0] = fma4(x0.x, w4, acc[0]);
            acc[1] = fma4(x0.y, w4, acc[1]);
            acc[2] = fma4(x0.z, w4, acc[2]);
            acc[3] = fma4(x0.w, w4, acc[3]);
            acc[4] = fma4(x1.x, w4, acc[4]);
            acc[5] = fma4(x1.y, w4, acc[5]);
            acc[6] = fma4(x1.z, w4, acc[6]);
            acc[7] = fma4(x1.w, w4, acc[7]);
        }
        __syncthreads();
    }

    const int b = r0 >> 9;
    const int sb = (r0 & 511) + rg * 8;
    if (vt == 0) {
#pragma unroll
        for (int r = 0; r < 8; ++r)
            *(float4*)(dst + (((long)b * HEAD + cq) * SEQ + sb + r) * 4) = acc[r];
    } else {
        const int col = c0 + cq * 4;
        const int h = col >> 3;
        const int off = col & 7;        // 0 or 4
#pragma unroll
        for (int r = 0; r < 8; ++r)
            *(float4*)(dst + (((long)b * HEAD + h) * SEQ + sb + r) * 8 + off) = acc[r];
    }
}

// ---------------------------------------------------------------------------
// proj2 (r5-proven, FROZEN): Q only, split-K x2 (Qa + Qb; attn sums on load).
// ---------------------------------------------------------------------------
__global__ __launch_bounds__(256, 8) void proj2_kernel(
    const float* __restrict__ A, const float* __restrict__ Wq,
    float* __restrict__ Qa, float* __restrict__ Qb)
{
    __shared__ float xt[32 * 32];   // 4 KB
    __shared__ float wt[32 * 64];   // 8 KB

    const int t  = threadIdx.x;
    const int kh = blockIdx.x & 1;
    const int bj = (blockIdx.x >> 1) & 3;
    const int br = blockIdx.x >> 3;
    const int r0 = br * 32;
    const int c0 = bj * 64;
    const int kb = kh * 256;
    float* dst = kh ? Qb : Qa;

    const int cq = t & 15;
    const int rr = t >> 4;
    const int rs = t & 31, kq = t >> 5;

    float4 acc[2];
    acc[0] = make_float4(0.f, 0.f, 0.f, 0.f);
    acc[1] = acc[0];

    for (int kc = 0; kc < 256; kc += 32) {
        const float4 xa = *(const float4*)(A + (long)(r0 + rs) * D_MODEL + kb + kc + kq * 4);
        xt[(kq * 4 + 0) * 32 + rs] = xa.x;
        xt[(kq * 4 + 1) * 32 + rs] = xa.y;
        xt[(kq * 4 + 2) * 32 + rs] = xa.z;
        xt[(kq * 4 + 3) * 32 + rs] = xa.w;
#pragma unroll
        for (int i = 0; i < 2; ++i) {
            const int row = i * 16 + (t >> 4);
            *(float4*)(wt + row * 64 + (t & 15) * 4) =
                *(const float4*)(Wq + (long)(kb + kc + row) * 256 + c0 + (t & 15) * 4);
        }
        __syncthreads();
#pragma unroll 4
        for (int k = 0; k < 32; ++k) {
            const float4 w4 = *(const float4*)(wt + k * 64 + cq * 4);
            const float2 x2 = *(const float2*)(xt + k * 32 + rr * 2);
            acc[0] = fma4(x2.x, w4, acc[0]);
            acc[1] = fma4(x2.y, w4, acc[1]);
        }
        __syncthreads();
    }

    const int b  = r0 >> 9;
    const int sb = (r0 & 511) + rr * 2;
    const int h  = (c0 >> 2) + cq;
#pragma unroll
    for (int r = 0; r < 2; ++r)
        *(float4*)(dst + (((long)b * HEAD + h) * SEQ + sb + r) * 4) = acc[r];
}

// ---------------------------------------------------------------------------
// Attention v2: ONE block per (b,h); 256 threads; TWO queries per thread
// (q = t and q = t+256). Halves wave count -> halves per-query LDS
// broadcast traffic and loop overhead vs r5 (which measured 75.6 us with a
// 24 us VALU floor). Causal handled INLINE via the multiplicative quirk:
// masked scores are EXACTLY 0 and participate in softmax with their V rows
// (r1/r2-refcheck-proven formulation) -> no lump/suffix-sum, no divergence.
// Scores in log2 domain (log2e/sqrt(DK) folded into Q).
// ---------------------------------------------------------------------------
template <int CAUSAL>
__device__ __forceinline__ void attn_core(
    const float* __restrict__ Kl, const float* __restrict__ Vl,
    const int q1, const int q2,
    const float4 qv1, const float4 qv2,
    float* __restrict__ O, const long obase1, const long obase2)
{
    float m1 = -INFINITY, l1 = 0.f, m2 = -INFINITY, l2 = 0.f;
    float A1[8], A2[8];
#pragma unroll
    for (int j = 0; j < 8; ++j) { A1[j] = 0.f; A2[j] = 0.f; }

    for (int s0 = 0; s0 < SEQ; s0 += 8) {
        float sc1[8], sc2[8];
#pragma unroll
        for (int i = 0; i < 8; ++i) {
            const float4 k4 = *(const float4*)(Kl + (s0 + i) * 4);
            const float d1 = fmaf(qv1.x, k4.x, fmaf(qv1.y, k4.y,
                             fmaf(qv1.z, k4.z, qv1.w * k4.w)));
            const float d2 = fmaf(qv2.x, k4.x, fmaf(qv2.y, k4.y,
                             fmaf(qv2.z, k4.z, qv2.w * k4.w)));
            sc1[i] = (CAUSAL && (s0 + i) > q1) ? 0.f : d1;
            sc2[i] = (CAUSAL && (s0 + i) > q2) ? 0.f : d2;
        }
        const float g1 = fmaxf(fmaxf(fmaxf(sc1[0], sc1[1]), fmaxf(sc1[2], sc1[3])),
                               fmaxf(fmaxf(sc1[4], sc1[5]), fmaxf(sc1[6], sc1[7])));
        const float g2 = fmaxf(fmaxf(fmaxf(sc2[0], sc2[1]), fmaxf(sc2[2], sc2[3])),
                               fmaxf(fmaxf(sc2[4], sc2[5]), fmaxf(sc2[6], sc2[7])));
        if (g1 > m1) {
            const float sc = __builtin_amdgcn_exp2f(m1 - g1);   // exp2(-inf)=0
            l1 *= sc;
#pragma unroll
            for (int j = 0; j < 8; ++j) A1[j] *= sc;
            m1 = g1;
        }
        if (g2 > m2) {
            const float sc = __builtin_amdgcn_exp2f(m2 - g2);
            l2 *= sc;
#pragma unroll
            for (int j = 0; j < 8; ++j) A2[j] *= sc;
            m2 = g2;
        }
#pragma unroll
        for (int i = 0; i < 8; ++i) {
            const float p1 = __builtin_amdgcn_exp2f(sc1[i] - m1);
            const float p2 = __builtin_amdgcn_exp2f(sc2[i] - m2);
            l1 += p1; l2 += p2;
            const float4 v0 = *(const float4*)(Vl + (s0 + i) * 8);
            const float4 v1 = *(const float4*)(Vl + (s0 + i) * 8 + 4);
            A1[0] = fmaf(p1, v0.x, A1[0]); A1[1] = fmaf(p1, v0.y, A1[1]);
            A1[2] = fmaf(p1, v0.z, A1[2]); A1[3] = fmaf(p1, v0.w, A1[3]);
            A1[4] = fmaf(p1, v1.x, A1[4]); A1[5] = fmaf(p1, v1.y, A1[5]);
            A1[6] = fmaf(p1, v1.z, A1[6]); A1[7] = fmaf(p1, v1.w, A1[7]);
            A2[0] = fmaf(p2, v0.x, A2[0]); A2[1] = fmaf(p2, v0.y, A2[1]);
            A2[2] = fmaf(p2, v0.z, A2[2]); A2[3] = fmaf(p2, v0.w, A2[3]);
            A2[4] = fmaf(p2, v1.x, A2[4]); A2[5] = fmaf(p2, v1.y, A2[5]);
            A2[6] = fmaf(p2, v1.z, A2[6]); A2[7] = fmaf(p2, v1.w, A2[7]);
        }
    }

    const float i1 = 1.0f / l1, i2 = 1.0f / l2;
    *(float4*)(O + obase1)     = make_float4(A1[0]*i1, A1[1]*i1, A1[2]*i1, A1[3]*i1);
    *(float4*)(O + obase1 + 4) = make_float4(A1[4]*i1, A1[5]*i1, A1[6]*i1, A1[7]*i1);
    *(float4*)(O + obase2)     = make_float4(A2[0]*i2, A2[1]*i2, A2[2]*i2, A2[3]*i2);
    *(float4*)(O + obase2 + 4) = make_float4(A2[4]*i2, A2[5]*i2, A2[6]*i2, A2[7]*i2);
}

__global__ __launch_bounds__(256) void attn_kernel(
    const float* __restrict__ Qa, const float* __restrict__ Qb,
    const float* __restrict__ K2, const float* __restrict__ V2,
    float* __restrict__ O, int causal)
{
    __shared__ float Kl[SEQ * DK];   //  8 KB
    __shared__ float Vl[SEQ * DV];   // 16 KB

    const int t  = threadIdx.x;
    const int bh = blockIdx.x;       // b*64 + h
    const int b  = bh >> 6;
    const int h  = bh & 63;

    const float4* Ks = (const float4*)(K2 + (long)bh * SEQ * DK);
    ((float4*)Kl)[t]       = Ks[t];
    ((float4*)Kl)[t + 256] = Ks[t + 256];
    const float4* Vs = (const float4*)(V2 + (long)bh * SEQ * DV);
#pragma unroll
    for (int i = 0; i < 4; ++i)
        ((float4*)Vl)[t + i * 256] = Vs[t + i * 256];

    const int q1 = t, q2 = t + 256;
    float4 qv1 = *(const float4*)(Qa + ((long)bh * SEQ + q1) * 4);
    float4 qv2 = *(const float4*)(Qa + ((long)bh * SEQ + q2) * 4);
    if (Qb) {                        // stage-2: sum split-K proj partials
        const float4 w1 = *(const float4*)(Qb + ((long)bh * SEQ + q1) * 4);
        const float4 w2 = *(const float4*)(Qb + ((long)bh * SEQ + q2) * 4);
        qv1.x += w1.x; qv1.y += w1.y; qv1.z += w1.z; qv1.w += w1.w;
        qv2.x += w2.x; qv2.y += w2.y; qv2.z += w2.z; qv2.w += w2.w;
    }
    const float cf = 0.5f * 1.44269504088896340736f;  // 1/sqrt(DK) * log2(e)
    qv1.x *= cf; qv1.y *= cf; qv1.z *= cf; qv1.w *= cf;
    qv2.x *= cf; qv2.y *= cf; qv2.z *= cf; qv2.w *= cf;

    __syncthreads();

    const long ob1 = (long)b * SEQ * 512 + (long)q1 * 512 + h * DV;
    const long ob2 = (long)b * SEQ * 512 + (long)q2 * 512 + h * DV;

    if (causal)
        attn_core<1>(Kl, Vl, q1, q2, qv1, qv2, O, ob1, ob2);
    else
        attn_core<0>(Kl, Vl, q1, q2, qv1, qv2, O, ob1, ob2);
}

// ---------------------------------------------------------------------------
// Fused residual + LayerNorm + MLP (512 -> 10 -> 512), r5-proven, FROZEN.
// ---------------------------------------------------------------------------
__global__ __launch_bounds__(256) void ln_mlp_kernel(
    const float* __restrict__ x, const float* __restrict__ fx,
    const float* __restrict__ g, const float* __restrict__ beta,
    const float* __restrict__ w1, const float* __restrict__ b1,
    const float* __restrict__ w2, const float* __restrict__ b2,
    float* __restrict__ out)
{
    const int t = threadIdx.x;
    const int lane = t & 63;
    const int row = blockIdx.x * 4 + (t >> 6);
    const long base = (long)row * D_MODEL;
    const int e0 = lane * 8;

    const float4 xa = *(const float4*)(x + base + e0);
    const float4 xb = *(const float4*)(x + base + e0 + 4);
    const float4 fa = *(const float4*)(fx + base + e0);
    const float4 fb = *(const float4*)(fx + base + e0 + 4);
    float z[8] = {xa.x+fa.x, xa.y+fa.y, xa.z+fa.z, xa.w+fa.w,
                  xb.x+fb.x, xb.y+fb.y, xb.z+fb.z, xb.w+fb.w};

    float sum = 0.f;
#pragma unroll
    for (int j = 0; j < 8; ++j) sum += z[j];
#pragma unroll
    for (int o = 32; o > 0; o >>= 1) sum += __shfl_xor(sum, o);
    float mu = sum * (1.0f / 512.0f);

    float d[8], ss = 0.f;
#pragma unroll
    for (int j = 0; j < 8; ++j) { d[j] = z[j] - mu; ss += d[j] * d[j]; }
#pragma unroll
    for (int o = 32; o > 0; o >>= 1) ss += __shfl_xor(ss, o);
    float rs = rsqrtf(ss * (1.0f / 512.0f) + 1e-5f);

    const float4 ga = *(const float4*)(g + e0);
    const float4 gb = *(const float4*)(g + e0 + 4);
    const float4 ba = *(const float4*)(beta + e0);
    const float4 bb = *(const float4*)(beta + e0 + 4);
    const float gg[8] = {ga.x,ga.y,ga.z,ga.w,gb.x,gb.y,gb.z,gb.w};
    const float bt[8] = {ba.x,ba.y,ba.z,ba.w,bb.x,bb.y,bb.z,bb.w};
    float y[8];
#pragma unroll
    for (int j = 0; j < 8; ++j) y[j] = d[j] * rs * gg[j] + bt[j];

    float part[HIDD];
#pragma unroll
    for (int i = 0; i < HIDD; ++i) {
        const float4 wa = *(const float4*)(w1 + i * 512 + e0);
        const float4 wb = *(const float4*)(w1 + i * 512 + e0 + 4);
        part[i] = y[0]*wa.x + y[1]*wa.y + y[2]*wa.z + y[3]*wa.w
                + y[4]*wb.x + y[5]*wb.y + y[6]*wb.z + y[7]*wb.w;
    }
#pragma unroll
    for (int i = 0; i < HIDD; ++i)
#pragma unroll
        for (int o = 32; o > 0; o >>= 1) part[i] += __shfl_xor(part[i], o);

    float hv[HIDD];
#pragma unroll
    for (int i = 0; i < HIDD; ++i) hv[i] = fmaxf(part[i] + b1[i], 0.f);

    float o8[8];
#pragma unroll
    for (int j = 0; j < 8; ++j) o8[j] = b2[e0 + j];
#pragma unroll
    for (int i = 0; i < HIDD; ++i)
#pragma unroll
        for (int j = 0; j < 8; ++j)
            o8[j] = fmaf(hv[i], w2[(long)(e0 + j) * 10 + i], o8[j]);

    *(float4*)(out + base + e0)     = make_float4(o8[0], o8[1], o8[2], o8[3]);
    *(float4*)(out + base + e0 + 4) = make_float4(o8[4], o8[5], o8[6], o8[7]);
}

extern "C" void kernel_launch(void* const* d_in, const int* in_sizes, int n_in,
                              void* d_out, int out_size, void* d_ws, size_t ws_size,
                              hipStream_t stream) {
    (void)in_sizes; (void)n_in; (void)out_size; (void)ws_size;
    const float* x    = (const float*)d_in[0];
    const float* xenc = (const float*)d_in[1];
    const float* Wq   = (const float*)d_in[2];
    const float* Wk   = (const float*)d_in[3];
    const float* Wv   = (const float*)d_in[4];
    const float* ln_g = (const float*)d_in[5];
    const float* ln_b = (const float*)d_in[6];
    const float* w1   = (const float*)d_in[7];
    const float* b1   = (const float*)d_in[8];
    const float* w2   = (const float*)d_in[9];
    const float* b2   = (const float*)d_in[10];
    float* out = (float*)d_out;

    // Workspace: 11.5M floats = 46 MiB, all regions disjoint (r5-proven).
    float* ws = (float*)d_ws;
    float* Q1 = ws;                    // [ 0M, 1M)  self Q   head-major
    float* K1 = ws +  1048576;         // [ 1M, 2M)  self K
    float* V1 = ws +  2097152;         // [ 2M, 4M)  self V
    float* Kc = ws +  4194304;         // [ 4M, 5M)  cross K (from x_enc)
    float* Vc = ws +  5242880;         // [ 5M, 7M)  cross V
    float* A  = ws +  7340032;         // [ 7M, 9M)  attn out, row-major
    float* Qa = ws +  9437184;         // [ 9M,10M)  stage-2 Q, k-half 0
    float* Qb = ws + 10485760;         // [10M,11M)  stage-2 Q, k-half 1

    proj_kernel<<<dim3(896), 256, 0, stream>>>(x, xenc, Wq, Wk, Wv,
                                               Q1, K1, V1, Kc, Vc);
    attn_kernel<<<dim3(BATCH * HEAD), 256, 0, stream>>>(
        Q1, nullptr, K1, V1, A, 1);
    proj2_kernel<<<dim3(1024), 256, 0, stream>>>(A, Wq, Qa, Qb);
    attn_kernel<<<dim3(BATCH * HEAD), 256, 0, stream>>>(
        Qa, Qb, Kc, Vc, A, 0);
    ln_mlp_kernel<<<dim3(1024), 256, 0, stream>>>(x, A, ln_g, ln_b,
                                                  w1, b1, w2, b2, out);
}